// Round 2
// baseline (3079.712 us; speedup 1.0000x reference)
//
#include <hip/hip_runtime.h>
#include <hip/hip_bf16.h>
#include <cstdint>

// Problem constants
#define NB    8
#define NCH   512
#define NPIXF 4096   // 64*64
#define NPIXP 1024   // 32*32
#define ICH   64
#define GCHN  128

__device__ __forceinline__ float lane_bcast(float v, int l) {
  return __int_as_float(__builtin_amdgcn_readlane(__float_as_int(v), l));
}

// ---------------------------------------------------------------------------
// Generic 1x1 conv = per-batch GEMM:  out[o][p] = sum_k w[o][k] * in[k][p] + bias[o]
// INMODE  0: in is channel-major  [b][K][NPIX]
//         1: in is pixel-major    [b][NPIX][K]
// OUTMODE 0: out channel-major [b][O][NPIX]; 1: out pixel-major [b][NPIX][O]
// Tile: 64 o x 64 pix, K-step 16, 256 threads, 4x4 micro-tile.
// ---------------------------------------------------------------------------
template<int O, int K, int NPIX, int INMODE, int OUTMODE>
__global__ __launch_bounds__(256) void conv1x1_gemm(
    const float* __restrict__ in, const float* __restrict__ w,
    const float* __restrict__ bias, float* __restrict__ out)
{
  const int b  = blockIdx.z;
  const int p0 = blockIdx.x * 64;
  const int o0 = blockIdx.y * 64;
  const float* inb  = in  + (size_t)b * K * NPIX;
  float*       outb = out + (size_t)b * O * NPIX;

  __shared__ float wS[16][64];
  __shared__ float xS[16][68];   // +4 pad: bank spread for transposed writes, keeps 16B align

  const int t  = threadIdx.x;
  const int ti = t >> 4, tj = t & 15;
  float acc[4][4] = {};

  for (int k0 = 0; k0 < K; k0 += 16) {
    // weights: wS[kt][o] = w[(o0+o)*K + k0+kt]
    {
      const int kt = t & 15, oo = t >> 4;
      #pragma unroll
      for (int r = 0; r < 4; ++r)
        wS[kt][oo + 16*r] = w[(size_t)(o0 + oo + 16*r) * K + k0 + kt];
    }
    if (INMODE == 0) {
      const int p = t & 63, kt = t >> 6;
      #pragma unroll
      for (int r = 0; r < 4; ++r)
        xS[kt + 4*r][p] = inb[(size_t)(k0 + kt + 4*r) * NPIX + p0 + p];
    } else {
      const int kt = t & 15, p = t >> 4;
      #pragma unroll
      for (int r = 0; r < 4; ++r)
        xS[kt][p + 16*r] = inb[(size_t)(p0 + p + 16*r) * K + k0 + kt];
    }
    __syncthreads();
    #pragma unroll
    for (int kt = 0; kt < 16; ++kt) {
      float a[4], bb[4];
      #pragma unroll
      for (int i = 0; i < 4; ++i) a[i]  = wS[kt][ti*4 + i];
      #pragma unroll
      for (int j = 0; j < 4; ++j) bb[j] = xS[kt][tj*4 + j];
      #pragma unroll
      for (int i = 0; i < 4; ++i)
        #pragma unroll
        for (int j = 0; j < 4; ++j)
          acc[i][j] += a[i] * bb[j];
    }
    __syncthreads();
  }

  float bv[4];
  #pragma unroll
  for (int i = 0; i < 4; ++i) bv[i] = bias[o0 + ti*4 + i];

  if (OUTMODE == 0) {
    #pragma unroll
    for (int i = 0; i < 4; ++i) {
      float4 v = make_float4(acc[i][0]+bv[i], acc[i][1]+bv[i], acc[i][2]+bv[i], acc[i][3]+bv[i]);
      *(float4*)(outb + (size_t)(o0 + ti*4 + i) * NPIX + p0 + tj*4) = v;
    }
  } else {
    #pragma unroll
    for (int j = 0; j < 4; ++j) {
      float4 v = make_float4(acc[0][j]+bv[0], acc[1][j]+bv[1], acc[2][j]+bv[2], acc[3][j]+bv[3]);
      *(float4*)(outb + (size_t)(p0 + tj*4 + j) * O + o0 + ti*4) = v;
    }
  }
}

// ---------------------------------------------------------------------------
// 2x2 maxpool, channel-major in/out: [B][O][4096] -> [B][O][1024]
// ---------------------------------------------------------------------------
template<int O>
__global__ __launch_bounds__(256) void pool_ch(const float* __restrict__ in,
                                               float* __restrict__ out)
{
  size_t idx = (size_t)blockIdx.x * 256 + threadIdx.x;   // over B*O*1024
  if (idx >= (size_t)NB * O * NPIXP) return;
  const int m = (int)(idx & 1023);
  const size_t bo = idx >> 10;
  const int my = m >> 5, mx = m & 31;
  const float* p = in + bo * NPIXF + my*128 + mx*2;
  out[idx] = fmaxf(fmaxf(p[0], p[1]), fmaxf(p[64], p[65]));
}

// 2x2 maxpool + transpose: [B][128][4096] -> [B][1024][128]
__global__ __launch_bounds__(256) void pool_g(const float* __restrict__ in,
                                              float* __restrict__ out)
{
  size_t idx = (size_t)blockIdx.x * 256 + threadIdx.x;   // m fastest (coalesced reads)
  if (idx >= (size_t)NB * GCHN * NPIXP) return;
  const int m = (int)(idx & 1023);
  const size_t t2 = idx >> 10;
  const int gc = (int)(t2 & 127);
  const int b  = (int)(t2 >> 7);
  const int my = m >> 5, mx = m & 31;
  const float* p = in + ((size_t)b * GCHN + gc) * NPIXF + my*128 + mx*2;
  out[((size_t)b * NPIXP + m) * GCHN + gc] = fmaxf(fmaxf(p[0], p[1]), fmaxf(p[64], p[65]));
}

// ---------------------------------------------------------------------------
// Fused attention: f = theta·phi (N=4096,M=1024,d=64), softmax over M,
// y = f·g (d_v=128).  Workgroup = 4 waves, wave handles 4 query rows.
// All 1024 scores live in 16 regs/lane (m = mt*64 + lane).
// ---------------------------------------------------------------------------
__global__ __launch_bounds__(256) void attn_kernel(
    const float* __restrict__ theta,  // [B][4096][64]
    const float* __restrict__ phi,    // [B][64][1024]
    const float* __restrict__ g,      // [B][1024][128]
    float* __restrict__ y)            // [B][4096][128]
{
  __shared__ float g_lds[64][128];

  const int wg   = blockIdx.x;          // 2048 = 8 * 256
  const int b    = wg >> 8;
  const int n0   = (wg & 255) << 4;     // 16 rows per workgroup
  const int t    = threadIdx.x;
  const int wave = t >> 6, lane = t & 63;
  const int row0 = n0 + wave * 4;

  // theta rows for this wave, one element per lane
  float th[4];
  #pragma unroll
  for (int r = 0; r < 4; ++r)
    th[r] = theta[((size_t)b * NPIXF + row0 + r) * ICH + lane];

  // ---- phase 1: scores --------------------------------------------------
  const float* phi_b = phi + (size_t)b * ICH * NPIXP;
  float s[4][16];
  #pragma unroll
  for (int mt = 0; mt < 16; ++mt) {
    float a0 = 0.f, a1 = 0.f, a2 = 0.f, a3 = 0.f;
    const float* pp = phi_b + mt*64 + lane;
    #pragma unroll 8
    for (int ic = 0; ic < ICH; ++ic) {
      float pv = pp[(size_t)ic * NPIXP];
      a0 += lane_bcast(th[0], ic) * pv;
      a1 += lane_bcast(th[1], ic) * pv;
      a2 += lane_bcast(th[2], ic) * pv;
      a3 += lane_bcast(th[3], ic) * pv;
    }
    s[0][mt] = a0; s[1][mt] = a1; s[2][mt] = a2; s[3][mt] = a3;
  }

  // ---- softmax over M (regs + wave butterfly) ---------------------------
  #pragma unroll
  for (int r = 0; r < 4; ++r) {
    float mx = s[r][0];
    #pragma unroll
    for (int j = 1; j < 16; ++j) mx = fmaxf(mx, s[r][j]);
    #pragma unroll
    for (int off = 32; off; off >>= 1) mx = fmaxf(mx, __shfl_xor(mx, off));
    float sum = 0.f;
    #pragma unroll
    for (int j = 0; j < 16; ++j) { float e = __expf(s[r][j] - mx); s[r][j] = e; sum += e; }
    #pragma unroll
    for (int off = 32; off; off >>= 1) sum += __shfl_xor(sum, off);
    const float inv = 1.0f / sum;
    #pragma unroll
    for (int j = 0; j < 16; ++j) s[r][j] *= inv;
  }

  // ---- phase 2: y = p · g  ---------------------------------------------
  float y0[4] = {0,0,0,0}, y1[4] = {0,0,0,0};
  const float* gb = g + (size_t)b * NPIXP * GCHN;
  #pragma unroll   // full unroll: keeps s[r][mt] statically indexed (no scratch)
  for (int mt = 0; mt < 16; ++mt) {
    __syncthreads();
    const float4* src = (const float4*)(gb + (size_t)mt * 64 * GCHN);
    float4* dst = (float4*)(&g_lds[0][0]);
    #pragma unroll
    for (int i = 0; i < 8; ++i) dst[t + 256*i] = src[t + 256*i];
    __syncthreads();
    for (int mm = 0; mm < 64; ++mm) {
      const float gv0 = g_lds[mm][lane];
      const float gv1 = g_lds[mm][64 + lane];
      #pragma unroll
      for (int r = 0; r < 4; ++r) {
        const float pm = lane_bcast(s[r][mt], mm);
        y0[r] += pm * gv0;
        y1[r] += pm * gv1;
      }
    }
  }

  #pragma unroll
  for (int r = 0; r < 4; ++r) {
    const size_t base = ((size_t)b * NPIXF + row0 + r) * GCHN;
    y[base + lane]      = y0[r];
    y[base + 64 + lane] = y1[r];
  }
}

// ---------------------------------------------------------------------------
// BatchNorm statistics: one block per channel; biased variance.
// ---------------------------------------------------------------------------
__global__ __launch_bounds__(256) void stats_kernel(const float* __restrict__ wy,
                                                    float* __restrict__ mean,
                                                    float* __restrict__ rstd)
{
  const int o = blockIdx.x;
  float s = 0.f, s2 = 0.f;
  for (int b = 0; b < NB; ++b) {
    const float* p = wy + ((size_t)b * NCH + o) * NPIXF;
    for (int i = threadIdx.x; i < NPIXF; i += 256) {
      const float v = p[i];
      s += v; s2 += v * v;
    }
  }
  #pragma unroll
  for (int off = 32; off; off >>= 1) { s += __shfl_xor(s, off); s2 += __shfl_xor(s2, off); }
  __shared__ float aux[8];
  const int wave = threadIdx.x >> 6, lane = threadIdx.x & 63;
  if (lane == 0) { aux[wave] = s; aux[4 + wave] = s2; }
  __syncthreads();
  if (threadIdx.x == 0) {
    const float S  = aux[0] + aux[1] + aux[2] + aux[3];
    const float S2 = aux[4] + aux[5] + aux[6] + aux[7];
    const float m  = S * (1.0f / 32768.0f);
    const float v  = S2 * (1.0f / 32768.0f) - m * m;
    mean[o] = m;
    rstd[o] = rsqrtf(v + 1e-5f);
  }
}

// ---------------------------------------------------------------------------
// Final (in place on d_out): out = (wy - mean) * rstd * gamma + beta + x
// wy lives in d_out (written by the wz GEMM); elementwise so in-place is safe.
// ---------------------------------------------------------------------------
__global__ __launch_bounds__(256) void final_kernel(
    float* __restrict__ wy_out, const float* __restrict__ x,
    const float* __restrict__ mean, const float* __restrict__ rstd,
    const float* __restrict__ gamma, const float* __restrict__ beta)
{
  const size_t idx = (size_t)blockIdx.x * 256 + threadIdx.x;  // float4 index
  const int c = (int)((idx >> 10) & 511);                     // 1024 float4 per (b,c)
  const float4 w4 = ((const float4*)wy_out)[idx];
  const float4 x4 = ((const float4*)x)[idx];
  const float sc = rstd[c] * gamma[c];
  const float sh = beta[c] - mean[c] * sc;
  float4 o;
  o.x = w4.x * sc + sh + x4.x;
  o.y = w4.y * sc + sh + x4.y;
  o.z = w4.z * sc + sh + x4.z;
  o.w = w4.w * sc + sh + x4.w;
  ((float4*)wy_out)[idx] = o;
}

// ---------------------------------------------------------------------------
extern "C" void kernel_launch(void* const* d_in, const int* in_sizes, int n_in,
                              void* d_out, int out_size, void* d_ws, size_t ws_size,
                              hipStream_t stream)
{
  const float* x        = (const float*)d_in[0];
  const float* g_w      = (const float*)d_in[1];
  const float* g_b      = (const float*)d_in[2];
  const float* theta_w  = (const float*)d_in[3];
  const float* theta_b  = (const float*)d_in[4];
  const float* phi_w    = (const float*)d_in[5];
  const float* phi_bv   = (const float*)d_in[6];
  const float* wz_w     = (const float*)d_in[7];
  const float* wz_b     = (const float*)d_in[8];
  const float* bn_gamma = (const float*)d_in[9];
  const float* bn_beta  = (const float*)d_in[10];
  float* out = (float*)d_out;

  // workspace layout (floats) — 14.16M floats = 56.6 MB total.
  // wy ([8][512][4096]) lives in d_out itself; final norm runs in place.
  float* ws      = (float*)d_ws;
  float* theta_t = ws;                 // [8][4096][64]   2,097,152
  float* phi_p   = ws + 2097152;       // [8][64][1024]     524,288
  float* g_p     = ws + 2621440;       // [8][1024][128]  1,048,576
  float* y_ws    = ws + 3670016;       // [8][4096][128]  4,194,304
  float* phi_f   = ws + 7864320;       // [8][64][4096]   2,097,152
  float* g_f     = ws + 9961472;       // [8][128][4096]  4,194,304
  float* mean_ws = ws + 14155776;      // [512]
  float* rstd_ws = ws + 14156288;      // [512]

  const dim3 blk(256);

  // theta: pixel-major output [b][n][64]
  conv1x1_gemm<64, 512, NPIXF, 0, 1><<<dim3(64, 1, NB), blk, 0, stream>>>(x, theta_w, theta_b, theta_t);
  // phi full-res: channel-major [b][64][4096]
  conv1x1_gemm<64, 512, NPIXF, 0, 0><<<dim3(64, 1, NB), blk, 0, stream>>>(x, phi_w, phi_bv, phi_f);
  // g full-res: channel-major [b][128][4096]
  conv1x1_gemm<128, 512, NPIXF, 0, 0><<<dim3(64, 2, NB), blk, 0, stream>>>(x, g_w, g_b, g_f);

  pool_ch<64><<<dim3((NB*64*NPIXP)/256), blk, 0, stream>>>(phi_f, phi_p);
  pool_g<<<dim3((NB*GCHN*NPIXP)/256), blk, 0, stream>>>(g_f, g_p);

  attn_kernel<<<dim3(NB * 256), blk, 0, stream>>>(theta_t, phi_p, g_p, y_ws);

  // wz: input pixel-major y [b][n][128], output channel-major wy -> d_out
  conv1x1_gemm<512, 128, NPIXF, 1, 0><<<dim3(64, 8, NB), blk, 0, stream>>>(y_ws, wz_w, wz_b, out);

  stats_kernel<<<dim3(512), blk, 0, stream>>>(out, mean_ws, rstd_ws);

  final_kernel<<<dim3((NB*NCH*NPIXF/4)/256), blk, 0, stream>>>(
      out, x, mean_ws, rstd_ws, bn_gamma, bn_beta);
}

// Round 4
// 832.530 us; speedup vs baseline: 3.6992x; 3.6992x over previous
//
#include <hip/hip_runtime.h>
#include <hip/hip_bf16.h>
#include <cstdint>

// Problem constants
#define NB    8
#define NCH   512
#define NPIXF 4096   // 64*64
#define NPIXP 1024   // 32*32
#define ICH   64
#define GCHN  128

__device__ __forceinline__ float lane_bcast(float v, int l) {
  return __int_as_float(__builtin_amdgcn_readlane(__float_as_int(v), l));
}

// ---------------------------------------------------------------------------
// Generic 1x1 conv = per-batch GEMM:  out[o][p] = sum_k w[o][k] * in[k][p] + bias[o]
// INMODE  0: in is channel-major  [b][K][NPIX]
//         1: in is pixel-major    [b][NPIX][K]
// OUTMODE 0: out channel-major [b][O][NPIX]; 1: out pixel-major [b][NPIX][O]
// Tile: 64 o x 64 pix, K-step 16, 256 threads, 4x4 micro-tile.
// ---------------------------------------------------------------------------
template<int O, int K, int NPIX, int INMODE, int OUTMODE>
__global__ __launch_bounds__(256) void conv1x1_gemm(
    const float* __restrict__ in, const float* __restrict__ w,
    const float* __restrict__ bias, float* __restrict__ out)
{
  const int b  = blockIdx.z;
  const int p0 = blockIdx.x * 64;
  const int o0 = blockIdx.y * 64;
  const float* inb  = in  + (size_t)b * K * NPIX;
  float*       outb = out + (size_t)b * O * NPIX;

  __shared__ float wS[16][64];
  __shared__ float xS[16][68];   // +4 pad: bank spread for transposed writes, keeps 16B align

  const int t  = threadIdx.x;
  const int ti = t >> 4, tj = t & 15;
  float acc[4][4] = {};

  for (int k0 = 0; k0 < K; k0 += 16) {
    // weights: wS[kt][o] = w[(o0+o)*K + k0+kt]
    {
      const int kt = t & 15, oo = t >> 4;
      #pragma unroll
      for (int r = 0; r < 4; ++r)
        wS[kt][oo + 16*r] = w[(size_t)(o0 + oo + 16*r) * K + k0 + kt];
    }
    if (INMODE == 0) {
      const int p = t & 63, kt = t >> 6;
      #pragma unroll
      for (int r = 0; r < 4; ++r)
        xS[kt + 4*r][p] = inb[(size_t)(k0 + kt + 4*r) * NPIX + p0 + p];
    } else {
      const int kt = t & 15, p = t >> 4;
      #pragma unroll
      for (int r = 0; r < 4; ++r)
        xS[kt][p + 16*r] = inb[(size_t)(p0 + p + 16*r) * K + k0 + kt];
    }
    __syncthreads();
    #pragma unroll
    for (int kt = 0; kt < 16; ++kt) {
      float a[4], bb[4];
      #pragma unroll
      for (int i = 0; i < 4; ++i) a[i]  = wS[kt][ti*4 + i];
      #pragma unroll
      for (int j = 0; j < 4; ++j) bb[j] = xS[kt][tj*4 + j];
      #pragma unroll
      for (int i = 0; i < 4; ++i)
        #pragma unroll
        for (int j = 0; j < 4; ++j)
          acc[i][j] += a[i] * bb[j];
    }
    __syncthreads();
  }

  float bv[4];
  #pragma unroll
  for (int i = 0; i < 4; ++i) bv[i] = bias[o0 + ti*4 + i];

  if (OUTMODE == 0) {
    #pragma unroll
    for (int i = 0; i < 4; ++i) {
      float4 v = make_float4(acc[i][0]+bv[i], acc[i][1]+bv[i], acc[i][2]+bv[i], acc[i][3]+bv[i]);
      *(float4*)(outb + (size_t)(o0 + ti*4 + i) * NPIX + p0 + tj*4) = v;
    }
  } else {
    #pragma unroll
    for (int j = 0; j < 4; ++j) {
      float4 v = make_float4(acc[0][j]+bv[0], acc[1][j]+bv[1], acc[2][j]+bv[2], acc[3][j]+bv[3]);
      *(float4*)(outb + (size_t)(p0 + tj*4 + j) * O + o0 + ti*4) = v;
    }
  }
}

// ---------------------------------------------------------------------------
// 2x2 maxpool, channel-major in/out: [B][O][4096] -> [B][O][1024]
// ---------------------------------------------------------------------------
template<int O>
__global__ __launch_bounds__(256) void pool_ch(const float* __restrict__ in,
                                               float* __restrict__ out)
{
  size_t idx = (size_t)blockIdx.x * 256 + threadIdx.x;   // over B*O*1024
  if (idx >= (size_t)NB * O * NPIXP) return;
  const int m = (int)(idx & 1023);
  const size_t bo = idx >> 10;
  const int my = m >> 5, mx = m & 31;
  const float* p = in + bo * NPIXF + my*128 + mx*2;
  out[idx] = fmaxf(fmaxf(p[0], p[1]), fmaxf(p[64], p[65]));
}

// 2x2 maxpool + transpose: [B][128][4096] -> [B][1024][128]
__global__ __launch_bounds__(256) void pool_g(const float* __restrict__ in,
                                              float* __restrict__ out)
{
  size_t idx = (size_t)blockIdx.x * 256 + threadIdx.x;   // m fastest (coalesced reads)
  if (idx >= (size_t)NB * GCHN * NPIXP) return;
  const int m = (int)(idx & 1023);
  const size_t t2 = idx >> 10;
  const int gc = (int)(t2 & 127);
  const int b  = (int)(t2 >> 7);
  const int my = m >> 5, mx = m & 31;
  const float* p = in + ((size_t)b * GCHN + gc) * NPIXF + my*128 + mx*2;
  out[((size_t)b * NPIXP + m) * GCHN + gc] = fmaxf(fmaxf(p[0], p[1]), fmaxf(p[64], p[65]));
}

// ---------------------------------------------------------------------------
// Fused attention: f = theta·phi (N=4096,M=1024,d=64), softmax over M,
// y = f·g (d_v=128).
// Block = 8 waves (512 thr); wave handles 2 query rows -> s[2][16] = 32 regs,
// total live state ~80 VGPR (round-2 fix: 4 rows/wave hit the 256-VGPR cap and
// spilled 2.7 GB of scratch). Workgroup covers 16 rows, same g-staging amort.
// ---------------------------------------------------------------------------
__global__ __launch_bounds__(512) void attn_kernel(
    const float* __restrict__ theta,  // [B][4096][64]
    const float* __restrict__ phi,    // [B][64][1024]
    const float* __restrict__ g,      // [B][1024][128]
    float* __restrict__ y)            // [B][4096][128]
{
  __shared__ float g_lds[64][128];

  const int wg   = blockIdx.x;          // 2048 = 8 * 256
  const int b    = wg >> 8;
  const int n0   = (wg & 255) << 4;     // 16 rows per workgroup
  const int t    = threadIdx.x;
  const int wave = t >> 6, lane = t & 63;
  const int row0 = n0 + wave * 2;

  // theta rows for this wave, one element per lane
  float th[2];
  #pragma unroll
  for (int r = 0; r < 2; ++r)
    th[r] = theta[((size_t)b * NPIXF + row0 + r) * ICH + lane];

  // ---- phase 1: scores (m = mt*64 + lane) -------------------------------
  const float* phi_b = phi + (size_t)b * ICH * NPIXP;
  float s[2][16];
  #pragma unroll
  for (int mt = 0; mt < 16; ++mt) {
    float a0 = 0.f, a1 = 0.f;
    const float* pp = phi_b + mt*64 + lane;
    #pragma unroll 8
    for (int ic = 0; ic < ICH; ++ic) {
      float pv = pp[(size_t)ic * NPIXP];
      a0 += lane_bcast(th[0], ic) * pv;
      a1 += lane_bcast(th[1], ic) * pv;
    }
    s[0][mt] = a0; s[1][mt] = a1;
  }

  // ---- softmax over M (regs + wave butterfly) ---------------------------
  #pragma unroll
  for (int r = 0; r < 2; ++r) {
    float mx = s[r][0];
    #pragma unroll
    for (int j = 1; j < 16; ++j) mx = fmaxf(mx, s[r][j]);
    #pragma unroll
    for (int off = 32; off; off >>= 1) mx = fmaxf(mx, __shfl_xor(mx, off));
    float sum = 0.f;
    #pragma unroll
    for (int j = 0; j < 16; ++j) { float e = __expf(s[r][j] - mx); s[r][j] = e; sum += e; }
    #pragma unroll
    for (int off = 32; off; off >>= 1) sum += __shfl_xor(sum, off);
    const float inv = 1.0f / sum;
    #pragma unroll
    for (int j = 0; j < 16; ++j) s[r][j] *= inv;
  }

  // ---- phase 2: y = p · g  ---------------------------------------------
  float y0[2] = {0,0}, y1[2] = {0,0};
  const float* gb = g + (size_t)b * NPIXP * GCHN;
  #pragma unroll   // full unroll: keeps s[r][mt] statically indexed (no scratch)
  for (int mt = 0; mt < 16; ++mt) {
    __syncthreads();
    const float4* src = (const float4*)(gb + (size_t)mt * 64 * GCHN);
    float4* dst = (float4*)(&g_lds[0][0]);
    #pragma unroll
    for (int i = 0; i < 4; ++i) dst[t + 512*i] = src[t + 512*i];
    __syncthreads();
    for (int mm = 0; mm < 64; ++mm) {
      const float gv0 = g_lds[mm][lane];
      const float gv1 = g_lds[mm][64 + lane];
      #pragma unroll
      for (int r = 0; r < 2; ++r) {
        const float pm = lane_bcast(s[r][mt], mm);
        y0[r] += pm * gv0;
        y1[r] += pm * gv1;
      }
    }
  }

  #pragma unroll
  for (int r = 0; r < 2; ++r) {
    const size_t base = ((size_t)b * NPIXF + row0 + r) * GCHN;
    y[base + lane]      = y0[r];
    y[base + 64 + lane] = y1[r];
  }
}

// ---------------------------------------------------------------------------
// BatchNorm statistics: one block per channel; biased variance.
// ---------------------------------------------------------------------------
__global__ __launch_bounds__(256) void stats_kernel(const float* __restrict__ wy,
                                                    float* __restrict__ mean,
                                                    float* __restrict__ rstd)
{
  const int o = blockIdx.x;
  float s = 0.f, s2 = 0.f;
  for (int b = 0; b < NB; ++b) {
    const float* p = wy + ((size_t)b * NCH + o) * NPIXF;
    for (int i = threadIdx.x; i < NPIXF; i += 256) {
      const float v = p[i];
      s += v; s2 += v * v;
    }
  }
  #pragma unroll
  for (int off = 32; off; off >>= 1) { s += __shfl_xor(s, off); s2 += __shfl_xor(s2, off); }
  __shared__ float aux[8];
  const int wave = threadIdx.x >> 6, lane = threadIdx.x & 63;
  if (lane == 0) { aux[wave] = s; aux[4 + wave] = s2; }
  __syncthreads();
  if (threadIdx.x == 0) {
    const float S  = aux[0] + aux[1] + aux[2] + aux[3];
    const float S2 = aux[4] + aux[5] + aux[6] + aux[7];
    const float m  = S * (1.0f / 32768.0f);
    const float v  = S2 * (1.0f / 32768.0f) - m * m;
    mean[o] = m;
    rstd[o] = rsqrtf(v + 1e-5f);
  }
}

// ---------------------------------------------------------------------------
// Final (in place on d_out): out = (wy - mean) * rstd * gamma + beta + x
// wy lives in d_out (written by the wz GEMM); elementwise so in-place is safe.
// ---------------------------------------------------------------------------
__global__ __launch_bounds__(256) void final_kernel(
    float* __restrict__ wy_out, const float* __restrict__ x,
    const float* __restrict__ mean, const float* __restrict__ rstd,
    const float* __restrict__ gamma, const float* __restrict__ beta)
{
  const size_t idx = (size_t)blockIdx.x * 256 + threadIdx.x;  // float4 index
  const int c = (int)((idx >> 10) & 511);                     // 1024 float4 per (b,c)
  const float4 w4 = ((const float4*)wy_out)[idx];
  const float4 x4 = ((const float4*)x)[idx];
  const float sc = rstd[c] * gamma[c];
  const float sh = beta[c] - mean[c] * sc;
  float4 o;
  o.x = w4.x * sc + sh + x4.x;
  o.y = w4.y * sc + sh + x4.y;
  o.z = w4.z * sc + sh + x4.z;
  o.w = w4.w * sc + sh + x4.w;
  ((float4*)wy_out)[idx] = o;
}

// ---------------------------------------------------------------------------
extern "C" void kernel_launch(void* const* d_in, const int* in_sizes, int n_in,
                              void* d_out, int out_size, void* d_ws, size_t ws_size,
                              hipStream_t stream)
{
  const float* x        = (const float*)d_in[0];
  const float* g_w      = (const float*)d_in[1];
  const float* g_b      = (const float*)d_in[2];
  const float* theta_w  = (const float*)d_in[3];
  const float* theta_b  = (const float*)d_in[4];
  const float* phi_w    = (const float*)d_in[5];
  const float* phi_bv   = (const float*)d_in[6];
  const float* wz_w     = (const float*)d_in[7];
  const float* wz_b     = (const float*)d_in[8];
  const float* bn_gamma = (const float*)d_in[9];
  const float* bn_beta  = (const float*)d_in[10];
  float* out = (float*)d_out;

  // workspace layout (floats) — 14.16M floats = 56.6 MB total.
  // wy ([8][512][4096]) lives in d_out itself; final norm runs in place.
  float* ws      = (float*)d_ws;
  float* theta_t = ws;                 // [8][4096][64]   2,097,152
  float* phi_p   = ws + 2097152;       // [8][64][1024]     524,288
  float* g_p     = ws + 2621440;       // [8][1024][128]  1,048,576
  float* y_ws    = ws + 3670016;       // [8][4096][128]  4,194,304
  float* phi_f   = ws + 7864320;       // [8][64][4096]   2,097,152
  float* g_f     = ws + 9961472;       // [8][128][4096]  4,194,304
  float* mean_ws = ws + 14155776;      // [512]
  float* rstd_ws = ws + 14156288;      // [512]

  const dim3 blk(256);

  // theta: pixel-major output [b][n][64]
  conv1x1_gemm<64, 512, NPIXF, 0, 1><<<dim3(64, 1, NB), blk, 0, stream>>>(x, theta_w, theta_b, theta_t);
  // phi full-res: channel-major [b][64][4096]
  conv1x1_gemm<64, 512, NPIXF, 0, 0><<<dim3(64, 1, NB), blk, 0, stream>>>(x, phi_w, phi_bv, phi_f);
  // g full-res: channel-major [b][128][4096]
  conv1x1_gemm<128, 512, NPIXF, 0, 0><<<dim3(64, 2, NB), blk, 0, stream>>>(x, g_w, g_b, g_f);

  pool_ch<64><<<dim3((NB*64*NPIXP)/256), blk, 0, stream>>>(phi_f, phi_p);
  pool_g<<<dim3((NB*GCHN*NPIXP)/256), blk, 0, stream>>>(g_f, g_p);

  attn_kernel<<<dim3(NB * 256), dim3(512), 0, stream>>>(theta_t, phi_p, g_p, y_ws);

  // wz: input pixel-major y [b][n][128], output channel-major wy -> d_out
  conv1x1_gemm<512, 128, NPIXF, 1, 0><<<dim3(64, 8, NB), blk, 0, stream>>>(y_ws, wz_w, wz_b, out);

  stats_kernel<<<dim3(512), blk, 0, stream>>>(out, mean_ws, rstd_ws);

  final_kernel<<<dim3((NB*NCH*NPIXF/4)/256), blk, 0, stream>>>(
      out, x, mean_ws, rstd_ws, bn_gamma, bn_beta);
}

// Round 5
// 513.713 us; speedup vs baseline: 5.9950x; 1.6206x over previous
//
#include <hip/hip_runtime.h>
#include <hip/hip_bf16.h>
#include <cstdint>

// Problem constants
#define NB    8
#define NCH   512
#define NPIXF 4096   // 64*64
#define NPIXP 1024   // 32*32
#define ICH   64
#define GCHN  128

typedef unsigned short u16;
typedef __attribute__((ext_vector_type(8))) short  bfrag;   // 8 bf16 (4 VGPR) MFMA A/B
typedef __attribute__((ext_vector_type(16))) float cfrag;   // 16 f32 MFMA C/D (32x32)

__device__ __forceinline__ u16 f2bf(float f) {              // RNE f32->bf16
  union { float f; uint32_t u; } c{f};
  return (u16)((c.u + 0x7fff + ((c.u >> 16) & 1)) >> 16);
}
__device__ __forceinline__ float bf2f(u16 h) {
  union { uint32_t u; float f; } c{(uint32_t)h << 16};
  return c.f;
}
__device__ __forceinline__ uint32_t pk_bf16(float lo, float hi) {
  uint32_t r;
  asm("v_cvt_pk_bf16_f32 %0, %1, %2" : "=v"(r) : "v"(lo), "v"(hi));
  return r;
}

// ---------------------------------------------------------------------------
// Generic 1x1 conv = per-batch GEMM:  out[o][p] = sum_k w[o][k] * in[k][p] + bias[o]
// INMODE  0: in channel-major [b][K][NPIX]; 1: in pixel-major [b][NPIX][K]
// OUTMODE 0: out channel-major f32; 1: out pixel-major
// OBF16 (with OUTMODE 1): write bf16 hi plane + lo plane (hi/lo split for MFMA)
// ---------------------------------------------------------------------------
template<int O, int K, int NPIX, int INMODE, int OUTMODE, int OBF16>
__global__ __launch_bounds__(256) void conv1x1_gemm(
    const float* __restrict__ in, const float* __restrict__ w,
    const float* __restrict__ bias, float* __restrict__ out)
{
  const int b  = blockIdx.z;
  const int p0 = blockIdx.x * 64;
  const int o0 = blockIdx.y * 64;
  const float* inb  = in  + (size_t)b * K * NPIX;
  float*       outb = out + (size_t)b * O * NPIX;

  __shared__ float wS[16][64];
  __shared__ float xS[16][68];   // +4 pad

  const int t  = threadIdx.x;
  const int ti = t >> 4, tj = t & 15;
  float acc[4][4] = {};

  for (int k0 = 0; k0 < K; k0 += 16) {
    {
      const int kt = t & 15, oo = t >> 4;
      #pragma unroll
      for (int r = 0; r < 4; ++r)
        wS[kt][oo + 16*r] = w[(size_t)(o0 + oo + 16*r) * K + k0 + kt];
    }
    if (INMODE == 0) {
      const int p = t & 63, kt = t >> 6;
      #pragma unroll
      for (int r = 0; r < 4; ++r)
        xS[kt + 4*r][p] = inb[(size_t)(k0 + kt + 4*r) * NPIX + p0 + p];
    } else {
      const int kt = t & 15, p = t >> 4;
      #pragma unroll
      for (int r = 0; r < 4; ++r)
        xS[kt][p + 16*r] = inb[(size_t)(p0 + p + 16*r) * K + k0 + kt];
    }
    __syncthreads();
    #pragma unroll
    for (int kt = 0; kt < 16; ++kt) {
      float a[4], bb[4];
      #pragma unroll
      for (int i = 0; i < 4; ++i) a[i]  = wS[kt][ti*4 + i];
      #pragma unroll
      for (int j = 0; j < 4; ++j) bb[j] = xS[kt][tj*4 + j];
      #pragma unroll
      for (int i = 0; i < 4; ++i)
        #pragma unroll
        for (int j = 0; j < 4; ++j)
          acc[i][j] += a[i] * bb[j];
    }
    __syncthreads();
  }

  float bv[4];
  #pragma unroll
  for (int i = 0; i < 4; ++i) bv[i] = bias[o0 + ti*4 + i];

  if (OUTMODE == 0) {
    #pragma unroll
    for (int i = 0; i < 4; ++i) {
      float4 v = make_float4(acc[i][0]+bv[i], acc[i][1]+bv[i], acc[i][2]+bv[i], acc[i][3]+bv[i]);
      *(float4*)(outb + (size_t)(o0 + ti*4 + i) * NPIX + p0 + tj*4) = v;
    }
  } else if (OBF16) {
    u16* ob = (u16*)out;
    const size_t LO = (size_t)NB * O * NPIX;     // lo plane offset (elements)
    #pragma unroll
    for (int j = 0; j < 4; ++j) {
      float vv[4];
      #pragma unroll
      for (int i = 0; i < 4; ++i) vv[i] = acc[i][j] + bv[i];
      ushort4 h4, l4;
      h4.x = f2bf(vv[0]); l4.x = f2bf(vv[0] - bf2f(h4.x));
      h4.y = f2bf(vv[1]); l4.y = f2bf(vv[1] - bf2f(h4.y));
      h4.z = f2bf(vv[2]); l4.z = f2bf(vv[2] - bf2f(h4.z));
      h4.w = f2bf(vv[3]); l4.w = f2bf(vv[3] - bf2f(h4.w));
      const size_t base = (size_t)b * O * NPIX + (size_t)(p0 + tj*4 + j) * O + o0 + ti*4;
      *(ushort4*)(ob + base)      = h4;
      *(ushort4*)(ob + LO + base) = l4;
    }
  } else {
    #pragma unroll
    for (int j = 0; j < 4; ++j) {
      float4 v = make_float4(acc[0][j]+bv[0], acc[1][j]+bv[1], acc[2][j]+bv[2], acc[3][j]+bv[3]);
      *(float4*)(outb + (size_t)(p0 + tj*4 + j) * O + o0 + ti*4) = v;
    }
  }
}

// ---------------------------------------------------------------------------
// phi pool: [8][64][4096] f32 -> [8][1024][64] bf16 hi + lo planes (transposed)
// ---------------------------------------------------------------------------
__global__ __launch_bounds__(256) void pool_phi_hl(const float* __restrict__ in,
                                                   u16* __restrict__ out)
{
  const int idx = blockIdx.x * 256 + threadIdx.x;   // [b][m][c], c fastest; 8*1024*64
  const int c = idx & 63;
  const int m = (idx >> 6) & 1023;
  const int b = idx >> 16;
  const int my = m >> 5, mxp = m & 31;
  const float* p = in + ((size_t)b * 64 + c) * NPIXF + my*128 + mxp*2;
  const float v = fmaxf(fmaxf(p[0], p[1]), fmaxf(p[64], p[65]));
  const u16 h = f2bf(v);
  out[idx] = h;
  out[idx + (size_t)NB * NPIXP * ICH] = f2bf(v - bf2f(h));
}

// g pool: [8][128][4096] f32 -> [8][128][1024] bf16 (channel-major, pooled)
__global__ __launch_bounds__(256) void pool_g_cm(const float* __restrict__ in,
                                                 u16* __restrict__ out)
{
  const int idx = blockIdx.x * 256 + threadIdx.x;   // [b][c][m], m fastest; 8*128*1024
  const int m  = idx & 1023;
  const int bc = idx >> 10;
  const int my = m >> 5, mxp = m & 31;
  const float* p = in + (size_t)bc * NPIXF + my*128 + mxp*2;
  out[idx] = f2bf(fmaxf(fmaxf(p[0], p[1]), fmaxf(p[64], p[65])));
}

// ---------------------------------------------------------------------------
// Fused MFMA attention. Wave = 32 q-rows; block = 4 waves; grid = 8 b * 32.
// S^T = mfma(A=phi[kv][d], B=theta[q][d]) -> D[kv][q]: col=lane&31=q,
// row kv=(reg&3)+8*(reg>>2)+4*(lane>>5)  [HW-verified C/D layout].
// Softmax per lane (q fixed): pass1 max sweep, pass2 recompute+exp+PV, /l at end.
// theta & phi are bf16 hi+lo split (3-term MFMA) to keep score error ~1e-3.
// P->A-frag remap: v_cvt_pk_bf16_f32 + v_permlane32_swap_b32 (m214 recipe).
// ---------------------------------------------------------------------------
__global__ __launch_bounds__(256) void attn_mfma(
    const u16* __restrict__ th16,   // [8][4096][64] hi plane, then lo plane
    const u16* __restrict__ ph16,   // [8][1024][64] hi plane, then lo plane
    const u16* __restrict__ g16,    // [8][128][1024]
    float* __restrict__ y)          // [8][4096][128] f32
{
  const int b    = blockIdx.x >> 5;
  const int n0   = (blockIdx.x & 31) * 128 + (threadIdx.x >> 6) * 32;
  const int lane = threadIdx.x & 63;
  const int q    = lane & 31, hi = lane >> 5;

  const size_t TH_LO = (size_t)NB * NPIXF * ICH;
  const size_t PH_LO = (size_t)NB * NPIXP * ICH;

  cfrag zero;
  #pragma unroll
  for (int r = 0; r < 16; ++r) zero[r] = 0.f;

  // theta fragments (B operand): lane holds theta[n0+q][16c + 8*hi + j]
  const u16* trow = th16 + ((size_t)b * NPIXF + n0 + q) * ICH + 8 * hi;
  bfrag tH[4], tL[4];
  #pragma unroll
  for (int c = 0; c < 4; ++c) {
    tH[c] = *(const bfrag*)(trow + 16*c);
    tL[c] = *(const bfrag*)(trow + TH_LO + 16*c);
  }

  // ---- pass 1: row max (hi-only precision is fine for a max) -------------
  float mx = -3.0e38f;
  for (int kt = 0; kt < 32; ++kt) {
    const u16* prow = ph16 + ((size_t)b * NPIXP + kt*32 + q) * ICH + 8 * hi;
    cfrag S = zero;
    #pragma unroll
    for (int c = 0; c < 4; ++c) {
      bfrag pa = *(const bfrag*)(prow + 16*c);
      S = __builtin_amdgcn_mfma_f32_32x32x16_bf16(pa, tH[c], S, 0, 0, 0);
    }
    #pragma unroll
    for (int r = 0; r < 16; ++r) mx = fmaxf(mx, S[r]);
  }
  mx = fmaxf(mx, __shfl_xor(mx, 32));

  // ---- pass 2: recompute S (split precision), P=exp, accumulate PV -------
  float l = 0.f;
  cfrag Y[4];
  #pragma unroll
  for (int t = 0; t < 4; ++t) Y[t] = zero;

  for (int kt = 0; kt < 32; ++kt) {
    const u16* prow = ph16 + ((size_t)b * NPIXP + kt*32 + q) * ICH + 8 * hi;
    cfrag S = zero;
    #pragma unroll
    for (int c = 0; c < 4; ++c) {
      bfrag pH = *(const bfrag*)(prow + 16*c);
      bfrag pL = *(const bfrag*)(prow + PH_LO + 16*c);
      S = __builtin_amdgcn_mfma_f32_32x32x16_bf16(pH, tH[c], S, 0, 0, 0);
      S = __builtin_amdgcn_mfma_f32_32x32x16_bf16(pH, tL[c], S, 0, 0, 0);
      S = __builtin_amdgcn_mfma_f32_32x32x16_bf16(pL, tH[c], S, 0, 0, 0);
    }
    float p[16];
    #pragma unroll
    for (int r = 0; r < 16; ++r) { p[r] = __expf(S[r] - mx); l += p[r]; }

    // remap P^T (col=q, row=kv) -> A-fragments A[q][kv] for two K=16 chunks
    union { uint32_t u[4]; bfrag v; } A0, A1;
    {
      uint32_t x0 = pk_bf16(p[0], p[1]),  y0 = pk_bf16(p[4], p[5]);
      asm volatile("v_permlane32_swap_b32 %0, %1" : "+v"(x0), "+v"(y0));
      uint32_t x1 = pk_bf16(p[2], p[3]),  y1 = pk_bf16(p[6], p[7]);
      asm volatile("v_permlane32_swap_b32 %0, %1" : "+v"(x1), "+v"(y1));
      A0.u[0] = x0; A0.u[1] = x1; A0.u[2] = y0; A0.u[3] = y1;
      uint32_t x2 = pk_bf16(p[8], p[9]),  y2 = pk_bf16(p[12], p[13]);
      asm volatile("v_permlane32_swap_b32 %0, %1" : "+v"(x2), "+v"(y2));
      uint32_t x3 = pk_bf16(p[10], p[11]), y3 = pk_bf16(p[14], p[15]);
      asm volatile("v_permlane32_swap_b32 %0, %1" : "+v"(x3), "+v"(y3));
      A1.u[0] = x2; A1.u[1] = x3; A1.u[2] = y2; A1.u[3] = y3;
    }

    // PV: Y[q][dv] += P[q][kv] * g[kv][dv]; B-frag from g_cm rows (dv, m)
    #pragma unroll
    for (int t = 0; t < 4; ++t) {
      const u16* gr = g16 + ((size_t)b * GCHN + t*32 + q) * NPIXP + kt*32 + 8*hi;
      bfrag g0 = *(const bfrag*)(gr);
      bfrag g1 = *(const bfrag*)(gr + 16);
      Y[t] = __builtin_amdgcn_mfma_f32_32x32x16_bf16(A0.v, g0, Y[t], 0, 0, 0);
      Y[t] = __builtin_amdgcn_mfma_f32_32x32x16_bf16(A1.v, g1, Y[t], 0, 0, 0);
    }
  }

  // ---- epilogue: divide by softmax denom, store ---------------------------
  l += __shfl_xor(l, 32);
  const float invl = 1.0f / l;
  #pragma unroll
  for (int r = 0; r < 16; ++r) {
    const int row = (r & 3) + 8 * (r >> 2) + 4 * hi;
    const float iv = __shfl(invl, row);
    float* yr = y + ((size_t)b * NPIXF + n0 + row) * GCHN + q;
    yr[0]  = Y[0][r] * iv;
    yr[32] = Y[1][r] * iv;
    yr[64] = Y[2][r] * iv;
    yr[96] = Y[3][r] * iv;
  }
}

// ---------------------------------------------------------------------------
// BatchNorm statistics: one block per channel; biased variance.
// ---------------------------------------------------------------------------
__global__ __launch_bounds__(256) void stats_kernel(const float* __restrict__ wy,
                                                    float* __restrict__ mean,
                                                    float* __restrict__ rstd)
{
  const int o = blockIdx.x;
  float s = 0.f, s2 = 0.f;
  for (int b = 0; b < NB; ++b) {
    const float* p = wy + ((size_t)b * NCH + o) * NPIXF;
    for (int i = threadIdx.x; i < NPIXF; i += 256) {
      const float v = p[i];
      s += v; s2 += v * v;
    }
  }
  #pragma unroll
  for (int off = 32; off; off >>= 1) { s += __shfl_xor(s, off); s2 += __shfl_xor(s2, off); }
  __shared__ float aux[8];
  const int wave = threadIdx.x >> 6, lane = threadIdx.x & 63;
  if (lane == 0) { aux[wave] = s; aux[4 + wave] = s2; }
  __syncthreads();
  if (threadIdx.x == 0) {
    const float S  = aux[0] + aux[1] + aux[2] + aux[3];
    const float S2 = aux[4] + aux[5] + aux[6] + aux[7];
    const float m  = S * (1.0f / 32768.0f);
    const float v  = S2 * (1.0f / 32768.0f) - m * m;
    mean[o] = m;
    rstd[o] = rsqrtf(v + 1e-5f);
  }
}

// ---------------------------------------------------------------------------
// Final (in place on d_out): out = (wy - mean) * rstd * gamma + beta + x
// ---------------------------------------------------------------------------
__global__ __launch_bounds__(256) void final_kernel(
    float* __restrict__ wy_out, const float* __restrict__ x,
    const float* __restrict__ mean, const float* __restrict__ rstd,
    const float* __restrict__ gamma, const float* __restrict__ beta)
{
  const size_t idx = (size_t)blockIdx.x * 256 + threadIdx.x;  // float4 index
  const int c = (int)((idx >> 10) & 511);
  const float4 w4 = ((const float4*)wy_out)[idx];
  const float4 x4 = ((const float4*)x)[idx];
  const float sc = rstd[c] * gamma[c];
  const float sh = beta[c] - mean[c] * sc;
  float4 o;
  o.x = w4.x * sc + sh + x4.x;
  o.y = w4.y * sc + sh + x4.y;
  o.z = w4.z * sc + sh + x4.z;
  o.w = w4.w * sc + sh + x4.w;
  ((float4*)wy_out)[idx] = o;
}

// ---------------------------------------------------------------------------
extern "C" void kernel_launch(void* const* d_in, const int* in_sizes, int n_in,
                              void* d_out, int out_size, void* d_ws, size_t ws_size,
                              hipStream_t stream)
{
  const float* x        = (const float*)d_in[0];
  const float* g_w      = (const float*)d_in[1];
  const float* g_b      = (const float*)d_in[2];
  const float* theta_w  = (const float*)d_in[3];
  const float* theta_b  = (const float*)d_in[4];
  const float* phi_w    = (const float*)d_in[5];
  const float* phi_bv   = (const float*)d_in[6];
  const float* wz_w     = (const float*)d_in[7];
  const float* wz_b     = (const float*)d_in[8];
  const float* bn_gamma = (const float*)d_in[9];
  const float* bn_beta  = (const float*)d_in[10];
  float* out = (float*)d_out;

  // workspace layout (floats) — ~13.63M floats = 54.5 MB.
  float* ws      = (float*)d_ws;
  u16*   theta16 = (u16*)ws;               // 2 planes * 8*4096*64 bf16 = 2,097,152 floats
  u16*   phi16   = (u16*)(ws + 2097152);   // 2 planes * 8*1024*64 bf16 =   524,288 floats
  u16*   g16     = (u16*)(ws + 2621440);   // 8*128*1024 bf16           =   524,288 floats
  float* y_ws    = ws + 3145728;           // [8][4096][128] f32        = 4,194,304 floats
  float* phi_f   = ws + 7340032;           // [8][64][4096] f32         = 2,097,152 floats
  float* g_f     = ws + 9437184;           // [8][128][4096] f32        = 4,194,304 floats
  float* mean_ws = ws + 13631488;          // [512]
  float* rstd_ws = ws + 13632000;          // [512]

  const dim3 blk(256);

  // theta: pixel-major bf16 hi/lo [b][n][64]
  conv1x1_gemm<64, 512, NPIXF, 0, 1, 1><<<dim3(64, 1, NB), blk, 0, stream>>>(x, theta_w, theta_b, (float*)theta16);
  // phi full-res: channel-major f32 [b][64][4096]
  conv1x1_gemm<64, 512, NPIXF, 0, 0, 0><<<dim3(64, 1, NB), blk, 0, stream>>>(x, phi_w, phi_bv, phi_f);
  // g full-res: channel-major f32 [b][128][4096]
  conv1x1_gemm<128, 512, NPIXF, 0, 0, 0><<<dim3(64, 2, NB), blk, 0, stream>>>(x, g_w, g_b, g_f);

  pool_phi_hl<<<dim3((NB*NPIXP*ICH)/256), blk, 0, stream>>>(phi_f, phi16);
  pool_g_cm<<<dim3((NB*GCHN*NPIXP)/256), blk, 0, stream>>>(g_f, g16);

  attn_mfma<<<dim3(256), blk, 0, stream>>>(theta16, phi16, g16, y_ws);

  // wz: input pixel-major y [b][n][128] f32, output channel-major -> d_out
  conv1x1_gemm<512, 128, NPIXF, 1, 0, 0><<<dim3(64, 8, NB), blk, 0, stream>>>(y_ws, wz_w, wz_b, out);

  stats_kernel<<<dim3(512), blk, 0, stream>>>(out, mean_ws, rstd_ws);

  final_kernel<<<dim3((NB*NCH*NPIXF/4)/256), blk, 0, stream>>>(
      out, x, mean_ws, rstd_ws, bn_gamma, bn_beta);
}

// Round 8
// 429.782 us; speedup vs baseline: 7.1658x; 1.1953x over previous
//
#include <hip/hip_runtime.h>
#include <hip/hip_bf16.h>
#include <cstdint>

// Problem constants
#define NB    8
#define NCH   512
#define NPIXF 4096   // 64*64
#define NPIXP 1024   // 32*32
#define ICH   64
#define GCHN  128

typedef unsigned short u16;
typedef __attribute__((ext_vector_type(8))) short   bfrag;   // 8 bf16 (4 VGPR) MFMA A/B
typedef __attribute__((ext_vector_type(8))) u16     ushort8;
typedef __attribute__((ext_vector_type(16))) float  cfrag;   // 16 f32 MFMA C/D (32x32)

__device__ __forceinline__ u16 f2bf(float f) {              // RNE f32->bf16
  union { float f; uint32_t u; } c{f};
  return (u16)((c.u + 0x7fff + ((c.u >> 16) & 1)) >> 16);
}
__device__ __forceinline__ float bf2f(u16 h) {
  union { uint32_t u; float f; } c{(uint32_t)h << 16};
  return c.f;
}
__device__ __forceinline__ uint32_t pk_bf16(float lo, float hi) {
  uint32_t r;
  asm("v_cvt_pk_bf16_f32 %0, %1, %2" : "=v"(r) : "v"(lo), "v"(hi));
  return r;
}

// ---------------------------------------------------------------------------
// fp32 VALU conv (kept for theta/phi: score path needs ~fp32 precision).
// INMODE 0: in channel-major [b][K][NPIX].
// OUTMODE 0: out channel-major f32; 1 + OBF16: pixel-major bf16 hi+lo planes.
// ---------------------------------------------------------------------------
template<int O, int K, int NPIX, int INMODE, int OUTMODE, int OBF16>
__global__ __launch_bounds__(256) void conv1x1_gemm(
    const float* __restrict__ in, const float* __restrict__ w,
    const float* __restrict__ bias, float* __restrict__ out)
{
  const int b  = blockIdx.z;
  const int p0 = blockIdx.x * 64;
  const int o0 = blockIdx.y * 64;
  const float* inb  = in  + (size_t)b * K * NPIX;
  float*       outb = out + (size_t)b * O * NPIX;

  __shared__ float wS[16][64];
  __shared__ float xS[16][68];

  const int t  = threadIdx.x;
  const int ti = t >> 4, tj = t & 15;
  float acc[4][4] = {};

  for (int k0 = 0; k0 < K; k0 += 16) {
    {
      const int kt = t & 15, oo = t >> 4;
      #pragma unroll
      for (int r = 0; r < 4; ++r)
        wS[kt][oo + 16*r] = w[(size_t)(o0 + oo + 16*r) * K + k0 + kt];
    }
    {
      const int p = t & 63, kt = t >> 6;
      #pragma unroll
      for (int r = 0; r < 4; ++r)
        xS[kt + 4*r][p] = inb[(size_t)(k0 + kt + 4*r) * NPIX + p0 + p];
    }
    __syncthreads();
    #pragma unroll
    for (int kt = 0; kt < 16; ++kt) {
      float a[4], bb[4];
      #pragma unroll
      for (int i = 0; i < 4; ++i) a[i]  = wS[kt][ti*4 + i];
      #pragma unroll
      for (int j = 0; j < 4; ++j) bb[j] = xS[kt][tj*4 + j];
      #pragma unroll
      for (int i = 0; i < 4; ++i)
        #pragma unroll
        for (int j = 0; j < 4; ++j)
          acc[i][j] += a[i] * bb[j];
    }
    __syncthreads();
  }

  float bv[4];
  #pragma unroll
  for (int i = 0; i < 4; ++i) bv[i] = bias[o0 + ti*4 + i];

  if (OUTMODE == 0) {
    #pragma unroll
    for (int i = 0; i < 4; ++i) {
      float4 v = make_float4(acc[i][0]+bv[i], acc[i][1]+bv[i], acc[i][2]+bv[i], acc[i][3]+bv[i]);
      *(float4*)(outb + (size_t)(o0 + ti*4 + i) * NPIX + p0 + tj*4) = v;
    }
  } else {
    u16* ob = (u16*)out;
    const size_t LO = (size_t)NB * O * NPIX;
    #pragma unroll
    for (int j = 0; j < 4; ++j) {
      float vv[4];
      #pragma unroll
      for (int i = 0; i < 4; ++i) vv[i] = acc[i][j] + bv[i];
      ushort4 h4, l4;
      h4.x = f2bf(vv[0]); l4.x = f2bf(vv[0] - bf2f(h4.x));
      h4.y = f2bf(vv[1]); l4.y = f2bf(vv[1] - bf2f(h4.y));
      h4.z = f2bf(vv[2]); l4.z = f2bf(vv[2] - bf2f(h4.z));
      h4.w = f2bf(vv[3]); l4.w = f2bf(vv[3] - bf2f(h4.w));
      const size_t base = (size_t)b * O * NPIX + (size_t)(p0 + tj*4 + j) * O + o0 + ti*4;
      *(ushort4*)(ob + base)      = h4;
      *(ushort4*)(ob + LO + base) = l4;
    }
  }
}

// ---------------------------------------------------------------------------
// phi pool: [8][64][4096] f32 -> [8][1024][64] bf16 hi + lo planes (transposed)
// ---------------------------------------------------------------------------
__global__ __launch_bounds__(256) void pool_phi_hl(const float* __restrict__ in,
                                                   u16* __restrict__ out)
{
  const int idx = blockIdx.x * 256 + threadIdx.x;   // [b][m][c], c fastest
  const int c = idx & 63;
  const int m = (idx >> 6) & 1023;
  const int b = idx >> 16;
  const int my = m >> 5, mxp = m & 31;
  const float* p = in + ((size_t)b * 64 + c) * NPIXF + my*128 + mxp*2;
  const float v = fmaxf(fmaxf(p[0], p[1]), fmaxf(p[64], p[65]));
  const u16 h = f2bf(v);
  out[idx] = h;
  out[idx + (size_t)NB * NPIXP * ICH] = f2bf(v - bf2f(h));
}

// ---------------------------------------------------------------------------
// x transpose+convert: [b][512][4096] f32 -> x_t [b][4096][512] bf16
// 64c x 64p tile through LDS; coalesced f32 reads, 32B-contig u16 writes.
// ---------------------------------------------------------------------------
__global__ __launch_bounds__(256) void xconvert(const float* __restrict__ x,
                                                u16* __restrict__ xt)
{
  __shared__ float tile[64][65];
  const int p0 = blockIdx.x * 64;
  const int c0 = blockIdx.y * 64;
  const int b  = blockIdx.z;
  const int t  = threadIdx.x;

  const int pl = t & 63, cr = t >> 6;
  #pragma unroll
  for (int r = 0; r < 16; ++r)
    tile[cr + 4*r][pl] = x[((size_t)b * NCH + c0 + cr + 4*r) * NPIXF + p0 + pl];
  __syncthreads();

  const int pw = t >> 2, cb = (t & 3) * 16;
  ushort8 v0, v1;
  #pragma unroll
  for (int i = 0; i < 8; ++i) v0[i] = f2bf(tile[cb + i][pw]);
  #pragma unroll
  for (int i = 0; i < 8; ++i) v1[i] = f2bf(tile[cb + 8 + i][pw]);
  u16* dst = xt + ((size_t)b * NPIXF + p0 + pw) * NCH + c0 + cb;
  *(ushort8*)(dst)     = v0;
  *(ushort8*)(dst + 8) = v1;
}

// generic f32 -> bf16 array convert (for weights)
__global__ __launch_bounds__(256) void bf16convert(const float* __restrict__ in,
                                                   u16* __restrict__ out, int n)
{
  const int i = blockIdx.x * 256 + threadIdx.x;
  if (i < n) out[i] = f2bf(in[i]);
}

// ---------------------------------------------------------------------------
// g conv (MFMA, single bf16) with FUSED 2x2 maxpool epilogue.
// Block 256 = 4 waves stacked along o (o0 = wave*32, O=128 covered).
// p-tile 128 = two image rows -> pool is in-registers:
//   vertical: max(acc[pg], acc[pg+2]); horizontal: shfl_xor(lane,1).
// Out: g16 [b][128][1024] bf16 channel-major pooled.
// ---------------------------------------------------------------------------
__global__ __launch_bounds__(256) void g_conv_mfma(
    const u16* __restrict__ xt,    // [8][4096][512] bf16
    const u16* __restrict__ wg,    // [128][512] bf16
    const float* __restrict__ gb,  // [128]
    u16* __restrict__ g16)         // [8][128][1024]
{
  const int b    = blockIdx.z;
  const int p0   = blockIdx.x * 128;
  const int lane = threadIdx.x & 63;
  const int o0   = (threadIdx.x >> 6) * 32;
  const int my   = p0 >> 7;                      // pooled row index

  cfrag acc[4];
  #pragma unroll
  for (int pg = 0; pg < 4; ++pg)
    #pragma unroll
    for (int r = 0; r < 16; ++r) acc[pg][r] = 0.f;

  const int kof = 8 * (lane >> 5);
  #pragma unroll 2
  for (int k0 = 0; k0 < NCH; k0 += 16) {
    bfrag a = *(const bfrag*)(wg + (size_t)(o0 + (lane & 31)) * NCH + k0 + kof);
    #pragma unroll
    for (int pg = 0; pg < 4; ++pg) {
      bfrag bx = *(const bfrag*)(xt + ((size_t)b * NPIXF + p0 + pg*32 + (lane & 31)) * NCH + k0 + kof);
      acc[pg] = __builtin_amdgcn_mfma_f32_32x32x16_bf16(a, bx, acc[pg], 0, 0, 0);
    }
  }

  #pragma unroll
  for (int r = 0; r < 16; ++r) {
    float v0 = fmaxf(acc[0][r], acc[2][r]);   // x 0..31  (row pair)
    float v1 = fmaxf(acc[1][r], acc[3][r]);   // x 32..63
    v0 = fmaxf(v0, __shfl_xor(v0, 1));
    v1 = fmaxf(v1, __shfl_xor(v1, 1));
    if (!(lane & 1)) {
      const int o   = o0 + (r & 3) + 8*(r >> 2) + 4*(lane >> 5);
      const int mxb = (lane & 31) >> 1;
      const float bvv = gb[o];
      u16* gr = g16 + ((size_t)b * GCHN + o) * NPIXP + my * 32;
      gr[mxb]      = f2bf(v0 + bvv);
      gr[16 + mxb] = f2bf(v1 + bvv);
    }
  }
}

// ---------------------------------------------------------------------------
// wz conv (MFMA, single bf16): out[o][p] = sum_dv wz[o][dv] y[p][dv] + bias.
// Block 512 = 8 waves stacked o (256 o per block, 2 o-blocks). K=128.
// ---------------------------------------------------------------------------
__global__ __launch_bounds__(512) void wz_conv_mfma(
    const u16* __restrict__ y16,   // [8][4096][128] bf16
    const u16* __restrict__ wz,    // [512][128] bf16
    const float* __restrict__ wzb, // [512]
    float* __restrict__ out)       // [8][512][4096] f32
{
  const int b    = blockIdx.z;
  const int p0   = blockIdx.x * 64;
  const int lane = threadIdx.x & 63;
  const int o0   = blockIdx.y * 256 + (threadIdx.x >> 6) * 32;

  cfrag acc[2];
  #pragma unroll
  for (int pg = 0; pg < 2; ++pg)
    #pragma unroll
    for (int r = 0; r < 16; ++r) acc[pg][r] = 0.f;

  const int kof = 8 * (lane >> 5);
  #pragma unroll
  for (int k0 = 0; k0 < GCHN; k0 += 16) {
    bfrag a = *(const bfrag*)(wz + (size_t)(o0 + (lane & 31)) * GCHN + k0 + kof);
    #pragma unroll
    for (int pg = 0; pg < 2; ++pg) {
      bfrag by = *(const bfrag*)(y16 + ((size_t)b * NPIXF + p0 + pg*32 + (lane & 31)) * GCHN + k0 + kof);
      acc[pg] = __builtin_amdgcn_mfma_f32_32x32x16_bf16(a, by, acc[pg], 0, 0, 0);
    }
  }

  #pragma unroll
  for (int r = 0; r < 16; ++r) {
    const int o = o0 + (r & 3) + 8*(r >> 2) + 4*(lane >> 5);
    const float bvv = wzb[o];
    float* orow = out + ((size_t)b * NCH + o) * NPIXF + p0 + (lane & 31);
    orow[0]  = acc[0][r] + bvv;
    orow[32] = acc[1][r] + bvv;
  }
}

// ---------------------------------------------------------------------------
// Fused MFMA attention (round-5, verified). Epilogue now writes y as bf16.
// ---------------------------------------------------------------------------
__global__ __launch_bounds__(256) void attn_mfma(
    const u16* __restrict__ th16,   // [8][4096][64] hi plane, then lo plane
    const u16* __restrict__ ph16,   // [8][1024][64] hi plane, then lo plane
    const u16* __restrict__ g16,    // [8][128][1024]
    u16* __restrict__ y16)          // [8][4096][128] bf16
{
  const int b    = blockIdx.x >> 5;
  const int n0   = (blockIdx.x & 31) * 128 + (threadIdx.x >> 6) * 32;
  const int lane = threadIdx.x & 63;
  const int q    = lane & 31, hi = lane >> 5;

  const size_t TH_LO = (size_t)NB * NPIXF * ICH;
  const size_t PH_LO = (size_t)NB * NPIXP * ICH;

  cfrag zero;
  #pragma unroll
  for (int r = 0; r < 16; ++r) zero[r] = 0.f;

  const u16* trow = th16 + ((size_t)b * NPIXF + n0 + q) * ICH + 8 * hi;
  bfrag tH[4], tL[4];
  #pragma unroll
  for (int c = 0; c < 4; ++c) {
    tH[c] = *(const bfrag*)(trow + 16*c);
    tL[c] = *(const bfrag*)(trow + TH_LO + 16*c);
  }

  // pass 1: row max
  float mx = -3.0e38f;
  for (int kt = 0; kt < 32; ++kt) {
    const u16* prow = ph16 + ((size_t)b * NPIXP + kt*32 + q) * ICH + 8 * hi;
    cfrag S = zero;
    #pragma unroll
    for (int c = 0; c < 4; ++c) {
      bfrag pa = *(const bfrag*)(prow + 16*c);
      S = __builtin_amdgcn_mfma_f32_32x32x16_bf16(pa, tH[c], S, 0, 0, 0);
    }
    #pragma unroll
    for (int r = 0; r < 16; ++r) mx = fmaxf(mx, S[r]);
  }
  mx = fmaxf(mx, __shfl_xor(mx, 32));

  // pass 2: recompute S (hi/lo split), P=exp, accumulate PV
  float l = 0.f;
  cfrag Y[4];
  #pragma unroll
  for (int t = 0; t < 4; ++t) Y[t] = zero;

  for (int kt = 0; kt < 32; ++kt) {
    const u16* prow = ph16 + ((size_t)b * NPIXP + kt*32 + q) * ICH + 8 * hi;
    cfrag S = zero;
    #pragma unroll
    for (int c = 0; c < 4; ++c) {
      bfrag pH = *(const bfrag*)(prow + 16*c);
      bfrag pL = *(const bfrag*)(prow + PH_LO + 16*c);
      S = __builtin_amdgcn_mfma_f32_32x32x16_bf16(pH, tH[c], S, 0, 0, 0);
      S = __builtin_amdgcn_mfma_f32_32x32x16_bf16(pH, tL[c], S, 0, 0, 0);
      S = __builtin_amdgcn_mfma_f32_32x32x16_bf16(pL, tH[c], S, 0, 0, 0);
    }
    float p[16];
    #pragma unroll
    for (int r = 0; r < 16; ++r) { p[r] = __expf(S[r] - mx); l += p[r]; }

    union { uint32_t u[4]; bfrag v; } A0, A1;
    {
      uint32_t x0 = pk_bf16(p[0], p[1]),  y0 = pk_bf16(p[4], p[5]);
      asm volatile("v_permlane32_swap_b32 %0, %1" : "+v"(x0), "+v"(y0));
      uint32_t x1 = pk_bf16(p[2], p[3]),  y1 = pk_bf16(p[6], p[7]);
      asm volatile("v_permlane32_swap_b32 %0, %1" : "+v"(x1), "+v"(y1));
      A0.u[0] = x0; A0.u[1] = x1; A0.u[2] = y0; A0.u[3] = y1;
      uint32_t x2 = pk_bf16(p[8], p[9]),  y2 = pk_bf16(p[12], p[13]);
      asm volatile("v_permlane32_swap_b32 %0, %1" : "+v"(x2), "+v"(y2));
      uint32_t x3 = pk_bf16(p[10], p[11]), y3 = pk_bf16(p[14], p[15]);
      asm volatile("v_permlane32_swap_b32 %0, %1" : "+v"(x3), "+v"(y3));
      A1.u[0] = x2; A1.u[1] = x3; A1.u[2] = y2; A1.u[3] = y3;
    }

    #pragma unroll
    for (int t = 0; t < 4; ++t) {
      const u16* gr = g16 + ((size_t)b * GCHN + t*32 + q) * NPIXP + kt*32 + 8*hi;
      bfrag g0 = *(const bfrag*)(gr);
      bfrag g1 = *(const bfrag*)(gr + 16);
      Y[t] = __builtin_amdgcn_mfma_f32_32x32x16_bf16(A0.v, g0, Y[t], 0, 0, 0);
      Y[t] = __builtin_amdgcn_mfma_f32_32x32x16_bf16(A1.v, g1, Y[t], 0, 0, 0);
    }
  }

  l += __shfl_xor(l, 32);
  const float invl = 1.0f / l;
  #pragma unroll
  for (int r = 0; r < 16; ++r) {
    const int row = (r & 3) + 8 * (r >> 2) + 4 * hi;
    const float iv = __shfl(invl, row);
    u16* yr = y16 + ((size_t)b * NPIXF + n0 + row) * GCHN + q;
    yr[0]  = f2bf(Y[0][r] * iv);
    yr[32] = f2bf(Y[1][r] * iv);
    yr[64] = f2bf(Y[2][r] * iv);
    yr[96] = f2bf(Y[3][r] * iv);
  }
}

// ---------------------------------------------------------------------------
// BatchNorm statistics
// ---------------------------------------------------------------------------
__global__ __launch_bounds__(256) void stats_kernel(const float* __restrict__ wy,
                                                    float* __restrict__ mean,
                                                    float* __restrict__ rstd)
{
  const int o = blockIdx.x;
  float s = 0.f, s2 = 0.f;
  for (int b = 0; b < NB; ++b) {
    const float* p = wy + ((size_t)b * NCH + o) * NPIXF;
    for (int i = threadIdx.x; i < NPIXF; i += 256) {
      const float v = p[i];
      s += v; s2 += v * v;
    }
  }
  #pragma unroll
  for (int off = 32; off; off >>= 1) { s += __shfl_xor(s, off); s2 += __shfl_xor(s2, off); }
  __shared__ float aux[8];
  const int wave = threadIdx.x >> 6, lane = threadIdx.x & 63;
  if (lane == 0) { aux[wave] = s; aux[4 + wave] = s2; }
  __syncthreads();
  if (threadIdx.x == 0) {
    const float S  = aux[0] + aux[1] + aux[2] + aux[3];
    const float S2 = aux[4] + aux[5] + aux[6] + aux[7];
    const float m  = S * (1.0f / 32768.0f);
    const float v  = S2 * (1.0f / 32768.0f) - m * m;
    mean[o] = m;
    rstd[o] = rsqrtf(v + 1e-5f);
  }
}

// ---------------------------------------------------------------------------
// Final (in place on d_out): out = (wy - mean) * rstd * gamma + beta + x
// ---------------------------------------------------------------------------
__global__ __launch_bounds__(256) void final_kernel(
    float* __restrict__ wy_out, const float* __restrict__ x,
    const float* __restrict__ mean, const float* __restrict__ rstd,
    const float* __restrict__ gamma, const float* __restrict__ beta)
{
  const size_t idx = (size_t)blockIdx.x * 256 + threadIdx.x;  // float4 index
  const int c = (int)((idx >> 10) & 511);
  const float4 w4 = ((const float4*)wy_out)[idx];
  const float4 x4 = ((const float4*)x)[idx];
  const float sc = rstd[c] * gamma[c];
  const float sh = beta[c] - mean[c] * sc;
  float4 o;
  o.x = w4.x * sc + sh + x4.x;
  o.y = w4.y * sc + sh + x4.y;
  o.z = w4.z * sc + sh + x4.z;
  o.w = w4.w * sc + sh + x4.w;
  ((float4*)wy_out)[idx] = o;
}

// ---------------------------------------------------------------------------
extern "C" void kernel_launch(void* const* d_in, const int* in_sizes, int n_in,
                              void* d_out, int out_size, void* d_ws, size_t ws_size,
                              hipStream_t stream)
{
  const float* x        = (const float*)d_in[0];
  const float* g_w      = (const float*)d_in[1];
  const float* g_b      = (const float*)d_in[2];
  const float* theta_w  = (const float*)d_in[3];
  const float* theta_b  = (const float*)d_in[4];
  const float* phi_w    = (const float*)d_in[5];
  const float* phi_bv   = (const float*)d_in[6];
  const float* wz_w     = (const float*)d_in[7];
  const float* wz_b     = (const float*)d_in[8];
  const float* bn_gamma = (const float*)d_in[9];
  const float* bn_beta  = (const float*)d_in[10];
  float* out = (float*)d_out;

  // workspace (floats) — 11.60M floats = 46.4 MB.
  // Region A (8.39M floats) hosts, in sequence: phi_f -> x_t -> y16.
  float* ws      = (float*)d_ws;
  u16*   theta16 = (u16*)ws;               // 2 planes 8*4096*64  = 2,097,152 floats
  u16*   phi16   = (u16*)(ws + 2097152);   // 2 planes 8*1024*64  =   524,288
  u16*   g16     = (u16*)(ws + 2621440);   // 8*128*1024          =   524,288
  u16*   wg16    = (u16*)(ws + 3145728);   // 128*512             =    32,768
  u16*   wz16    = (u16*)(ws + 3178496);   // 512*128             =    32,768
  float* mean_ws = ws + 3211264;           // [512]
  float* rstd_ws = ws + 3211776;           // [512]
  float* regionA = ws + 3212288;           // 8,388,608 floats
  float* phi_f   = regionA;                // [8][64][4096] f32 (dead before xconvert)
  u16*   x_t     = (u16*)regionA;          // [8][4096][512] bf16 (dead after g conv)
  u16*   y16     = (u16*)regionA;          // [8][4096][128] bf16 (written by attn)

  const dim3 blk(256);

  // theta: pixel-major bf16 hi/lo [b][n][64]  (fp32 VALU, full precision)
  conv1x1_gemm<64, 512, NPIXF, 0, 1, 1><<<dim3(64, 1, NB), blk, 0, stream>>>(x, theta_w, theta_b, (float*)theta16);
  // phi full-res: channel-major f32 -> pooled hi/lo bf16
  conv1x1_gemm<64, 512, NPIXF, 0, 0, 0><<<dim3(64, 1, NB), blk, 0, stream>>>(x, phi_w, phi_bv, phi_f);
  pool_phi_hl<<<dim3((NB*NPIXP*ICH)/256), blk, 0, stream>>>(phi_f, phi16);

  // x -> pixel-major bf16 (overwrites phi_f region; phi_f is consumed)
  xconvert<<<dim3(64, 8, NB), blk, 0, stream>>>(x, x_t);
  bf16convert<<<dim3(256), blk, 0, stream>>>(g_w, wg16, GCHN * NCH);
  bf16convert<<<dim3(256), blk, 0, stream>>>(wz_w, wz16, NCH * GCHN);

  // g conv: MFMA + fused 2x2 maxpool -> g16 channel-major bf16
  g_conv_mfma<<<dim3(32, 1, NB), blk, 0, stream>>>(x_t, wg16, g_b, g16);

  // attention -> y16 bf16 (overwrites x_t region; x_t is consumed)
  attn_mfma<<<dim3(256), blk, 0, stream>>>(theta16, phi16, g16, y16);

  // wz conv: MFMA -> d_out channel-major f32
  wz_conv_mfma<<<dim3(64, 2, NB), dim3(512), 0, stream>>>(y16, wz16, wz_b, out);

  stats_kernel<<<dim3(512), blk, 0, stream>>>(out, mean_ws, rstd_ws);

  final_kernel<<<dim3((NB*NCH*NPIXF/4)/256), blk, 0, stream>>>(
      out, x, mean_ws, rstd_ws, bn_gamma, bn_beta);
}